// Round 5
// baseline (926.087 us; speedup 1.0000x reference)
//
#include <hip/hip_runtime.h>

#define HW 3136      // 56*56
#define SHS4 232     // sH row stride: 4*56=224 px + 8 pad

// Fused residual-stage: grouped3x3 conv + bias + BN + ReLU -> (LDS) -> grouped1x1 conv
// + bias + BN + ReLU -> global.
// v5: 4-row tiles + k-split double-pass (sH holds 32 of 64 channels at a time ->
// 29.7 KB LDS, 4 blocks/CU) -> phase 2 gets 4 outs x 14 px per thread (8 LDS reads
// per output, half of v2/v4). Phase 1 is wave-per-row coalesced with halo via 3
// overlapping coalesced loads (no shfl: v4 showed shfl = +37us VALU). Weights/BN in
// phase 1 are wave-uniform -> s_loads. Interleaved px (2*pg+32*j) -> conflict-free
// LDS reads + 128B-contiguous stores.
__global__ __launch_bounds__(256, 4) void fused_stage(
    const float* __restrict__ in,    // [32,256,56,56]
    const float* __restrict__ gw,    // [4,64,4,3,3]  (i,k,cc,dy,dx)
    const float* __restrict__ gb,    // [256] flat (i*64+k)
    const float* __restrict__ bnag, const float* __restrict__ bnab,
    const float* __restrict__ bnam, const float* __restrict__ bnav,
    const float* __restrict__ pw,    // [256,64]
    const float* __restrict__ pb,    // [256]
    const float* __restrict__ bnbg, const float* __restrict__ bnbb,
    const float* __restrict__ bnbm, const float* __restrict__ bnbv,
    float* __restrict__ out)         // [32,256,56,56]
{
    __shared__ float sH[32 * SHS4];  // 29696 B: half of the intermediate channels

    const int tid = threadIdx.x;

    // XCD-aware decode: the 4 g-blocks for one (b,t) tile are 8 apart -> same XCD.
    const int idx  = blockIdx.x;     // grid = 1792 = 8 xcd * 4 g * 56 slots
    const int xcd  = idx & 7;
    const int qq   = idx >> 3;       // 0..223
    const int g    = qq & 3;
    const int slot = qq >> 2;        // 0..55
    const int u    = slot * 8 + xcd; // 0..447
    const int b    = u / 14;
    const int t    = u - b * 14;     // 4-row tile 0..13
    const int y0   = t * 4;

    const int l  = tid & 63;                                  // lane = pixel
    const int wv = __builtin_amdgcn_readfirstlane(tid >> 6);  // wave id 0..3 (SGPR)

    // phase-2 ownership (constant across halves)
    const int og = tid >> 4;         // 0..15 -> out channels og*4 .. og*4+3
    const int pg = tid & 15;         // 0..15 -> px 2*pg + 32*j, j=0..6 (14 px)

    float a2[4][14];                 // held across both k-halves
#pragma unroll
    for (int i = 0; i < 4; ++i)
#pragma unroll
        for (int xx = 0; xx < 14; ++xx) a2[i][xx] = 0.f;

#pragma unroll 1
    for (int h = 0; h < 2; ++h) {
        // ---- phase 1: grouped 3x3 conv, channels k = h*32 .. h*32+31 ----
        // Each wave handles 8 k sequentially; lane l computes out px l of 4 rows.
#pragma unroll 1
        for (int kk = 0; kk < 8; ++kk) {
            const int k = h * 32 + wv * 8 + kk;     // wave-uniform
            const int c = g * 64 + k;

            const float* wk = gw + (size_t)(g * 64 + k) * 36;  // uniform -> s_load
            float acc[4];
#pragma unroll
            for (int r = 0; r < 4; ++r) acc[r] = 0.f;

            const float* chp0 = in + ((size_t)(b * 256 + k * 4)) * HW;
#pragma unroll
            for (int cc = 0; cc < 4; ++cc) {
                const float* chp = chp0 + cc * HW;
#pragma unroll
                for (int ry = 0; ry < 6; ++ry) {
                    const int gy = y0 - 1 + ry;              // block-uniform
                    if ((unsigned)gy >= 56u) continue;       // zero-pad rows
                    const float* rp = chp + gy * 56;
                    // out px l needs in px l-1, l, l+1: 3 overlapping coalesced loads
                    const float c0 = (l >= 1 && l < 56) ? rp[l - 1] : 0.f;
                    const float c1 = (l < 56)           ? rp[l]     : 0.f;
                    const float c2 = (l < 55)           ? rp[l + 1] : 0.f;
#pragma unroll
                    for (int r = 0; r < 4; ++r) {
                        const int wi = ry - r;               // weight row index
                        if (wi < 0 || wi > 2) continue;      // dead-code after unroll
                        const float w0 = wk[cc * 9 + wi * 3 + 0];
                        const float w1 = wk[cc * 9 + wi * 3 + 1];
                        const float w2 = wk[cc * 9 + wi * 3 + 2];
                        acc[r] += fmaf(w2, c2, fmaf(w1, c1, w0 * c0));
                    }
                }
            }

            // bias + BN-a + ReLU -> sH (uniform BN params -> s_load)
            const float sc = bnag[c] * rsqrtf(bnav[c] + 1e-5f);
            const float sh = fmaf(gb[c], sc, bnab[c] - bnam[c] * sc);
            if (l < 56) {
                float* sp = &sH[(k & 31) * SHS4 + l];
                sp[0]   = fmaxf(fmaf(acc[0], sc, sh), 0.f);
                sp[56]  = fmaxf(fmaf(acc[1], sc, sh), 0.f);
                sp[112] = fmaxf(fmaf(acc[2], sc, sh), 0.f);
                sp[168] = fmaxf(fmaf(acc[3], sc, sh), 0.f);
            }
        }
        __syncthreads();

        // ---- phase 2: accumulate this half's 32 channels into a2[4][14] ----
        const float* wp = pw + (size_t)(g * 64 + og * 4) * 64 + h * 32;
#pragma unroll 1
        for (int c4 = 0; c4 < 32; c4 += 4) {
            const float4 wv0 = *(const float4*)(wp + 0 * 64 + c4);  // L1-hit
            const float4 wv1 = *(const float4*)(wp + 1 * 64 + c4);
            const float4 wv2 = *(const float4*)(wp + 2 * 64 + c4);
            const float4 wv3 = *(const float4*)(wp + 3 * 64 + c4);
            const float w0a[4] = {wv0.x, wv0.y, wv0.z, wv0.w};
            const float w1a[4] = {wv1.x, wv1.y, wv1.z, wv1.w};
            const float w2a[4] = {wv2.x, wv2.y, wv2.z, wv2.w};
            const float w3a[4] = {wv3.x, wv3.y, wv3.z, wv3.w};
#pragma unroll
            for (int q2 = 0; q2 < 4; ++q2) {
                const float* hrow = &sH[(c4 + q2) * SHS4];
                const float wa = w0a[q2], wb = w1a[q2], wc = w2a[q2], wd = w3a[q2];
#pragma unroll
                for (int j = 0; j < 7; ++j) {
                    // px pair 2*pg+32*j: banks 2*pg,(+1) -> 16 addr-pairs, conflict-free
                    const float2 hv = *(const float2*)&hrow[2 * pg + 32 * j];
                    a2[0][2*j]   = fmaf(wa, hv.x, a2[0][2*j]);
                    a2[0][2*j+1] = fmaf(wa, hv.y, a2[0][2*j+1]);
                    a2[1][2*j]   = fmaf(wb, hv.x, a2[1][2*j]);
                    a2[1][2*j+1] = fmaf(wb, hv.y, a2[1][2*j+1]);
                    a2[2][2*j]   = fmaf(wc, hv.x, a2[2][2*j]);
                    a2[2][2*j+1] = fmaf(wc, hv.y, a2[2][2*j+1]);
                    a2[3][2*j]   = fmaf(wd, hv.x, a2[3][2*j]);
                    a2[3][2*j+1] = fmaf(wd, hv.y, a2[3][2*j+1]);
                }
            }
        }
        __syncthreads();   // protect sH before next half overwrites it
    }

    // ---- bias + BN-b + ReLU -> global (128B-contiguous stores per channel) ----
#pragma unroll
    for (int i = 0; i < 4; ++i) {
        const int o = g * 64 + og * 4 + i;
        const float sc = bnbg[o] * rsqrtf(bnbv[o] + 1e-5f);
        const float sh = fmaf(pb[o], sc, bnbb[o] - bnbm[o] * sc);
        float* op = out + ((size_t)(b * 256 + o)) * HW + y0 * 56;
#pragma unroll
        for (int j = 0; j < 7; ++j) {
            float v0 = fmaxf(fmaf(a2[i][2*j],   sc, sh), 0.f);
            float v1 = fmaxf(fmaf(a2[i][2*j+1], sc, sh), 0.f);
            *(float2*)(op + 2 * pg + 32 * j) = make_float2(v0, v1);
        }
    }
}

extern "C" void kernel_launch(void* const* d_in, const int* in_sizes, int n_in,
                              void* d_out, int out_size, void* d_ws, size_t ws_size,
                              hipStream_t stream) {
    const float* x     = (const float*)d_in[0];
    const float* w1    = (const float*)d_in[1];
    const float* b1    = (const float*)d_in[2];
    const float* bn1ag = (const float*)d_in[3];
    const float* bn1ab = (const float*)d_in[4];
    const float* bn1am = (const float*)d_in[5];
    const float* bn1av = (const float*)d_in[6];
    const float* pw1   = (const float*)d_in[7];
    const float* pb1   = (const float*)d_in[8];
    const float* bn1bg = (const float*)d_in[9];
    const float* bn1bb = (const float*)d_in[10];
    const float* bn1bm = (const float*)d_in[11];
    const float* bn1bv = (const float*)d_in[12];
    const float* w2    = (const float*)d_in[13];
    const float* b2    = (const float*)d_in[14];
    const float* bn2ag = (const float*)d_in[15];
    const float* bn2ab = (const float*)d_in[16];
    const float* bn2am = (const float*)d_in[17];
    const float* bn2av = (const float*)d_in[18];
    const float* pw2   = (const float*)d_in[19];
    const float* pb2   = (const float*)d_in[20];
    const float* bn2bg = (const float*)d_in[21];
    const float* bn2bb = (const float*)d_in[22];
    const float* bn2bm = (const float*)d_in[23];
    const float* bn2bv = (const float*)d_in[24];

    float* mid  = (float*)d_ws;      // 32*256*56*56*4 = 102,760,448 B
    float* outp = (float*)d_out;

    const int grid = 32 * 4 * 14;    // (b, g, 4-row tile) via XCD-aware decode

    fused_stage<<<grid, 256, 0, stream>>>(x,   w1, b1, bn1ag, bn1ab, bn1am, bn1av,
                                          pw1, pb1, bn1bg, bn1bb, bn1bm, bn1bv, mid);
    fused_stage<<<grid, 256, 0, stream>>>(mid, w2, b2, bn2ag, bn2ab, bn2am, bn2av,
                                          pw2, pb2, bn2bg, bn2bb, bn2bm, bn2bv, outp);
}